// Round 1
// baseline (195.724 us; speedup 1.0000x reference)
//
#include <hip/hip_runtime.h>
#include <hip/hip_bf16.h>

#define B_  8
#define T_  2048
#define E_  1024
#define H_  64
#define BT_ (B_*T_)

typedef __attribute__((ext_vector_type(8))) __bf16 bf16x8;
typedef __attribute__((ext_vector_type(4))) float  f32x4;

__device__ __forceinline__ unsigned short f2bfu(float f) {
    union { float f; unsigned u; } v; v.f = f;
    unsigned r = v.u + 0x7fffu + ((v.u >> 16) & 1u);
    return (unsigned short)(r >> 16);
}

// ---------------- Phase 1: QKV projection ----------------
// x [BT, E] fp32  @  W [E, H] fp32  -> q,k [BT,H] bf16 (q pre-scaled by 1/8),
// v stored transposed per batch: vt [B][H][T] bf16.
// Block = 64 tokens, 256 threads (4 waves, 16 rows each). K-chunk = 32.
__global__ __launch_bounds__(256, 2)
void qkv_kernel(const float* __restrict__ x,
                const float* __restrict__ Wq,
                const float* __restrict__ Wk,
                const float* __restrict__ Wv,
                unsigned short* __restrict__ qb,
                unsigned short* __restrict__ kb,
                unsigned short* __restrict__ vtb)
{
    // padded strides: 40 shorts = 80B (16B-aligned rows, 2-way bank alias only)
    __shared__ unsigned short xs[64 * 40];
    __shared__ unsigned short wt[3][64 * 40];   // [mat][h][k]  (W transposed)

    const int tid  = threadIdx.x;
    const int wave = tid >> 6;
    const int lane = tid & 63;
    const int quad = lane >> 4;
    const int col  = lane & 15;
    const long r0  = (long)blockIdx.x * 64;

    f32x4 acc[3][4];
#pragma unroll
    for (int m = 0; m < 3; ++m)
#pragma unroll
        for (int n = 0; n < 4; ++n)
            acc[m][n] = (f32x4){0.f, 0.f, 0.f, 0.f};

    const float* W[3] = {Wq, Wk, Wv};

    const int xrow = tid >> 2;          // 0..63
    const int xk   = (tid & 3) * 8;     // 0,8,16,24
    const int wk   = tid >> 3;          // 0..31
    const int wh   = (tid & 7) * 8;     // 0..56

    for (int k0 = 0; k0 < E_; k0 += 32) {
        // ---- load globals into regs ----
        const float* xp = x + (r0 + xrow) * E_ + k0 + xk;
        float4 f0 = ((const float4*)xp)[0];
        float4 f1 = ((const float4*)xp)[1];
        unsigned pack[4];
        pack[0] = f2bfu(f0.x) | ((unsigned)f2bfu(f0.y) << 16);
        pack[1] = f2bfu(f0.z) | ((unsigned)f2bfu(f0.w) << 16);
        pack[2] = f2bfu(f1.x) | ((unsigned)f2bfu(f1.y) << 16);
        pack[3] = f2bfu(f1.z) | ((unsigned)f2bfu(f1.w) << 16);

        float wg[3][8];
#pragma unroll
        for (int m = 0; m < 3; ++m) {
            const float* wp = W[m] + (long)(k0 + wk) * H_ + wh;
            float4 g0 = ((const float4*)wp)[0];
            float4 g1 = ((const float4*)wp)[1];
            wg[m][0]=g0.x; wg[m][1]=g0.y; wg[m][2]=g0.z; wg[m][3]=g0.w;
            wg[m][4]=g1.x; wg[m][5]=g1.y; wg[m][6]=g1.z; wg[m][7]=g1.w;
        }

        __syncthreads();   // protect previous iteration's LDS reads

        *(uint4*)&xs[xrow * 40 + xk] = *(uint4*)pack;
#pragma unroll
        for (int m = 0; m < 3; ++m)
#pragma unroll
            for (int j = 0; j < 8; ++j)
                wt[m][(wh + j) * 40 + wk] = f2bfu(wg[m][j]);

        __syncthreads();

        // ---- MFMA ----
        bf16x8 af = *(const bf16x8*)&xs[(wave * 16 + col) * 40 + quad * 8];
#pragma unroll
        for (int m = 0; m < 3; ++m)
#pragma unroll
            for (int n = 0; n < 4; ++n) {
                bf16x8 bfg = *(const bf16x8*)&wt[m][(n * 16 + col) * 40 + quad * 8];
                acc[m][n] = __builtin_amdgcn_mfma_f32_16x16x32_bf16(af, bfg, acc[m][n], 0, 0, 0);
            }
    }

    // ---- epilogue: C/D layout col=lane&15, row=quad*4+reg ----
    const int bidx = (int)(r0 >> 11);
#pragma unroll
    for (int n = 0; n < 4; ++n) {
        int h = n * 16 + col;
#pragma unroll
        for (int r = 0; r < 4; ++r) {
            long t = r0 + wave * 16 + quad * 4 + r;
            qb[t * H_ + h] = f2bfu(acc[0][n][r] * 0.125f);   // fold 1/sqrt(H)
            kb[t * H_ + h] = f2bfu(acc[1][n][r]);
            vtb[((long)(bidx * H_ + h)) * T_ + (t & (T_ - 1))] = f2bfu(acc[2][n][r]);
        }
    }
}

// ---------------- Phase 2: causal flash attention ----------------
// Block = one (batch, 64-row q-tile). 256 threads, wave handles 16 q-rows.
// Iterate key tiles of 64; online softmax; P goes C-layout -> LDS -> A-layout.
#define TS 72   // padded row stride (shorts): 144B rows, 16B aligned, 2-way alias

__global__ __launch_bounds__(256, 2)
void attn_kernel(const unsigned short* __restrict__ qb,
                 const unsigned short* __restrict__ kb,
                 const unsigned short* __restrict__ vtb,
                 float* __restrict__ out)
{
    __shared__ unsigned short qs[64 * TS];
    __shared__ unsigned short ks[64 * TS];
    __shared__ unsigned short vs[64 * TS];      // [h][t]
    __shared__ unsigned short ps[4][16 * TS];   // per-wave P scratch

    const int tid  = threadIdx.x;
    const int wave = tid >> 6;
    const int lane = tid & 63;
    const int quad = lane >> 4;
    const int col  = lane & 15;
    const int qt   = blockIdx.x & 31;
    const int b    = blockIdx.x >> 5;

    // stage Q tile (64x64 bf16), padded rows
    {
        const uint4* src = (const uint4*)(qb + ((long)b * T_ + qt * 64) * H_);
#pragma unroll
        for (int i = 0; i < 2; ++i) {
            int idx = tid + i * 256;          // 0..511 uint4s
            int row = idx >> 3, c = idx & 7;
            *(uint4*)&qs[row * TS + c * 8] = src[idx];
        }
    }

    f32x4 o[4];
    float m_i[4], l_i[4];
#pragma unroll
    for (int n = 0; n < 4; ++n) o[n] = (f32x4){0.f, 0.f, 0.f, 0.f};
#pragma unroll
    for (int r = 0; r < 4; ++r) { m_i[r] = -1e30f; l_i[r] = 0.f; }

    for (int s = 0; s <= qt; ++s) {
        // ---- stage K tile [64 keys][64 h] and V^T tile [64 h][64 keys] ----
        {
            const uint4* ksrc = (const uint4*)(kb + ((long)b * T_ + s * 64) * H_);
#pragma unroll
            for (int i = 0; i < 2; ++i) {
                int idx = tid + i * 256;
                int row = idx >> 3, c = idx & 7;
                *(uint4*)&ks[row * TS + c * 8] = ksrc[idx];
                const uint4* vsrc =
                    (const uint4*)(vtb + ((long)(b * H_ + row)) * T_ + s * 64) + c;
                *(uint4*)&vs[row * TS + c * 8] = *vsrc;
            }
        }
        __syncthreads();

        // ---- S = Q K^T  (4 key-subtiles of 16) ----
        bf16x8 qa0 = *(const bf16x8*)&qs[(wave * 16 + col) * TS + quad * 8];
        bf16x8 qa1 = *(const bf16x8*)&qs[(wave * 16 + col) * TS + quad * 8 + 32];
        f32x4 sa[4];
#pragma unroll
        for (int kt = 0; kt < 4; ++kt) {
            bf16x8 kf0 = *(const bf16x8*)&ks[(kt * 16 + col) * TS + quad * 8];
            bf16x8 kf1 = *(const bf16x8*)&ks[(kt * 16 + col) * TS + quad * 8 + 32];
            sa[kt] = (f32x4){0.f, 0.f, 0.f, 0.f};
            sa[kt] = __builtin_amdgcn_mfma_f32_16x16x32_bf16(qa0, kf0, sa[kt], 0, 0, 0);
            sa[kt] = __builtin_amdgcn_mfma_f32_16x16x32_bf16(qa1, kf1, sa[kt], 0, 0, 0);
        }

        // ---- causal mask (only diagonal tile needs it) ----
        if (s == qt) {
#pragma unroll
            for (int kt = 0; kt < 4; ++kt) {
                int kg = kt * 16 + col;
#pragma unroll
                for (int r = 0; r < 4; ++r) {
                    int qg = wave * 16 + quad * 4 + r;
                    if (kg > qg) sa[kt][r] = -1e30f;
                }
            }
        }

        // ---- online softmax: row max over 64 keys ----
        float mx[4];
#pragma unroll
        for (int r = 0; r < 4; ++r)
            mx[r] = fmaxf(fmaxf(sa[0][r], sa[1][r]), fmaxf(sa[2][r], sa[3][r]));
#pragma unroll
        for (int off = 1; off < 16; off <<= 1)
#pragma unroll
            for (int r = 0; r < 4; ++r)
                mx[r] = fmaxf(mx[r], __shfl_xor(mx[r], off, 64));

        float alpha[4], mnew[4];
#pragma unroll
        for (int r = 0; r < 4; ++r) {
            mnew[r]  = fmaxf(m_i[r], mx[r]);
            alpha[r] = __builtin_amdgcn_exp2f((m_i[r] - mnew[r]) * 1.44269504f);
            m_i[r]   = mnew[r];
        }

        // ---- P = exp(S - m), row-sum, spill P to LDS (C-layout) ----
        float rs[4] = {0.f, 0.f, 0.f, 0.f};
#pragma unroll
        for (int kt = 0; kt < 4; ++kt)
#pragma unroll
            for (int r = 0; r < 4; ++r) {
                float p = __builtin_amdgcn_exp2f((sa[kt][r] - mnew[r]) * 1.44269504f);
                rs[r] += p;
                ps[wave][(quad * 4 + r) * TS + kt * 16 + col] = f2bfu(p);
            }
#pragma unroll
        for (int off = 1; off < 16; off <<= 1)
#pragma unroll
            for (int r = 0; r < 4; ++r)
                rs[r] += __shfl_xor(rs[r], off, 64);
#pragma unroll
        for (int r = 0; r < 4; ++r)
            l_i[r] = l_i[r] * alpha[r] + rs[r];

        // ---- rescale O, then O += P @ V ----
#pragma unroll
        for (int n = 0; n < 4; ++n)
#pragma unroll
            for (int r = 0; r < 4; ++r)
                o[n][r] *= alpha[r];

        bf16x8 pa0 = *(const bf16x8*)&ps[wave][col * TS + quad * 8];
        bf16x8 pa1 = *(const bf16x8*)&ps[wave][col * TS + quad * 8 + 32];
#pragma unroll
        for (int n = 0; n < 4; ++n) {
            bf16x8 vf0 = *(const bf16x8*)&vs[(n * 16 + col) * TS + quad * 8];
            bf16x8 vf1 = *(const bf16x8*)&vs[(n * 16 + col) * TS + quad * 8 + 32];
            o[n] = __builtin_amdgcn_mfma_f32_16x16x32_bf16(pa0, vf0, o[n], 0, 0, 0);
            o[n] = __builtin_amdgcn_mfma_f32_16x16x32_bf16(pa1, vf1, o[n], 0, 0, 0);
        }
        __syncthreads();
    }

    // ---- epilogue: divide by l, store fp32 ----
#pragma unroll
    for (int r = 0; r < 4; ++r) {
        float inv = 1.0f / l_i[r];
        long row = (long)b * T_ + qt * 64 + wave * 16 + quad * 4 + r;
#pragma unroll
        for (int n = 0; n < 4; ++n)
            out[row * H_ + n * 16 + col] = o[n][r] * inv;
    }
}

extern "C" void kernel_launch(void* const* d_in, const int* in_sizes, int n_in,
                              void* d_out, int out_size, void* d_ws, size_t ws_size,
                              hipStream_t stream) {
    (void)in_sizes; (void)n_in; (void)out_size; (void)ws_size;
    const float* x  = (const float*)d_in[0];
    const float* Wq = (const float*)d_in[1];
    const float* Wk = (const float*)d_in[2];
    const float* Wv = (const float*)d_in[3];

    unsigned short* qb  = (unsigned short*)d_ws;               // 2 MB
    unsigned short* kb  = qb + (size_t)BT_ * H_;               // 2 MB
    unsigned short* vtb = kb + (size_t)BT_ * H_;               // 2 MB

    qkv_kernel<<<BT_ / 64, 256, 0, stream>>>(x, Wq, Wk, Wv, qb, kb, vtb);
    attn_kernel<<<B_ * (T_ / 64), 256, 0, stream>>>(qb, kb, vtb, (float*)d_out);
}